// Round 5
// baseline (323.522 us; speedup 1.0000x reference)
//
#include <hip/hip_runtime.h>
#include <math.h>
#include <stdint.h>

#define ND_ROWS 16384
#define DDIM    256
#define KCODES  8192
#define NSEG    128        // 64-code segments
#define NRG     8          // row groups (XCD-affine), 2048 rows each

typedef _Float16 f16x4 __attribute__((ext_vector_type(4)));
typedef _Float16 f16x8 __attribute__((ext_vector_type(8)));
typedef float    f32x4v __attribute__((ext_vector_type(4)));
typedef float    f32x16 __attribute__((ext_vector_type(16)));

// ---------------------------------------------------------------------------
// ws layout (bytes):
//   minpair [0,        131072)   u64[16384]  (memset 0xFF each call)
//   counts  [131072,   163840)   int[8192]   (memset 0 each call)
//   parts   [163840,   196608)   de[4096] | dq[4096]
//   neF     [196608,   229376)   float[8192] = ||e||^2
//   Xp      [229376,   17006592) x as MFMA B-operand fragments, 16.8 MB:
//            per 32-row block rb (32 KB): hi q=0..15 then lo q=0..15; unit
//            (rb,q) = 1 KB; 16B chunk index within unit = (kg<<5)|rl holding
//            halves k = q*16 + kg*8 .. +8 of row rl. (coalesced 1KB/instr)
//   Bp      [17006592, 25395200) 8192 x 512 f16 = [-2e_hi(256) | -2e_lo(256)]
// ---------------------------------------------------------------------------

__device__ __attribute__((always_inline)) inline void load_lds16(const void* g, void* l) {
    __builtin_amdgcn_global_load_lds((const __attribute__((address_space(1))) void*)g,
                                     (__attribute__((address_space(3))) void*)l, 16, 0, 0);
}

// one wave per vector. x -> B-operand fragment layout (hi/lo split, unscaled).
// codebook -> row-major [-2e_hi | -2e_lo] (-2 folded in) + float ne table.
__global__ __launch_bounds__(256) void prep_kernel(const float* __restrict__ x,
                                                   const float* __restrict__ emb,
                                                   _Float16* __restrict__ Xp,
                                                   _Float16* __restrict__ Bp,
                                                   float* __restrict__ neF) {
    int wave = (blockIdx.x << 2) + (threadIdx.x >> 6);   // [0, 24576)
    int lane = threadIdx.x & 63;
    if (wave < ND_ROWS) {
        const float* src = x + (size_t)wave * DDIM;
        float4 v = ((const float4*)src)[lane];           // k = lane*4 .. +4
        f16x4 hi, lo;
        hi[0] = (_Float16)v.x; lo[0] = (_Float16)(v.x - (float)hi[0]);
        hi[1] = (_Float16)v.y; lo[1] = (_Float16)(v.y - (float)hi[1]);
        hi[2] = (_Float16)v.z; lo[2] = (_Float16)(v.z - (float)hi[2]);
        hi[3] = (_Float16)v.w; lo[3] = (_Float16)(v.w - (float)hi[3]);
        int rb = wave >> 5, rl = wave & 31;
        // q = lane>>2, kg = (lane>>1)&1, j0 = (lane&1)*4  (f16-unit offsets)
        size_t off = (size_t)rb * 16384 + ((lane >> 2) << 9)
                   + (((lane >> 1) & 1) << 8) + (rl << 3) + ((lane & 1) << 2);
        *(f16x4*)(Xp + off)        = hi;
        *(f16x4*)(Xp + off + 8192) = lo;                 // lo block: +16 KB
    } else {
        int r = wave - ND_ROWS;
        const float* src = emb + (size_t)r * DDIM;
        float4 v = ((const float4*)src)[lane];
        float s = v.x*v.x + v.y*v.y + v.z*v.z + v.w*v.w;  // ||e||^2 of original e
        #pragma unroll
        for (int m = 32; m; m >>= 1) s += __shfl_xor(s, m, 64);
        float4 t;                                         // fold the -2 in
        t.x = -2.0f * v.x; t.y = -2.0f * v.y; t.z = -2.0f * v.z; t.w = -2.0f * v.w;
        f16x4 hi, lo;
        hi[0] = (_Float16)t.x; lo[0] = (_Float16)(t.x - (float)hi[0]);
        hi[1] = (_Float16)t.y; lo[1] = (_Float16)(t.y - (float)hi[1]);
        hi[2] = (_Float16)t.z; lo[2] = (_Float16)(t.z - (float)hi[2]);
        hi[3] = (_Float16)t.w; lo[3] = (_Float16)(t.w - (float)hi[3]);
        _Float16* dst = Bp + (size_t)r * 512;
        *(f16x4*)(dst + lane * 4)       = hi;
        *(f16x4*)(dst + 256 + lane * 4) = lo;
        if (lane == 0) neF[r] = s;
    }
}

// Barrier-free argmin GEMM, codes-as-M, mfma_f32_32x32x16_f16, 2-chunk blocked.
// R15 = R14's conflict-free transposed code slab + 2-stage register pipeline
// with a HARD #pragma unroll 1 on the q-loop.
//
// Post-mortem chain:
//   R11/R14: MfmaUtil pinned ~44% with just-in-time loads; VGPR 64 + AGPR 64
//     = exactly the 128-reg 4-wave cap -> zero regs for prefetch.
//   R14: bank conflicts 8.39M -> 0 but time unchanged -> conflicts were
//     hidden under load-wait stalls (regime gate); layout kept as prereq.
//   R13: the spill culprit was '#pragma unroll' = FULL unroll of the staged
//     q-loop (hoisting across 8 bodies), not the staging itself.
// Fix: unroll 1 bounds liveness at ~150 regs (64 AGPR acc + 2x32 VGPR stage
// + addr) under launch_bounds(512,2). Occupancy 1 block/CU (2 waves/SIMD);
// per SIMD 2 waves x 384 cyc/q MFMA demand, each wave issues its 16 prefetch
// loads a full q-step (>=384 cyc > L2 latency) ahead under the other wave's
// burst. Tail branch avoided via (q+2)&15 wrap (1 redundant L2-hit prefetch
// per c2). setprio(1) wraps MFMA clusters (2 drifting waves to arbitrate).
#define MFMA16(A, B, C) __builtin_amdgcn_mfma_f32_32x32x16_f16(A, B, C, 0, 0, 0)

#define DECL_STAGE(P) f16x8 P##xh0, P##xl0, P##xh1, P##xl1, \
                            P##c0, P##d0, P##c1, P##d1;

// x fragments: 2 chunks x (hi,lo). chunk 1 at xb0 + 32768; lo at +16384.
#define LOADX(P, qq) { \
    P##xh0 = *(const f16x8*)(xb0 + (qq) * 1024); \
    P##xl0 = *(const f16x8*)(xb0 + 16384 + (qq) * 1024); \
    P##xh1 = *(const f16x8*)(xb1 + (qq) * 1024); \
    P##xl1 = *(const f16x8*)(xb1 + 16384 + (qq) * 1024); }

// code fragments from the transposed slab (conflict-free, compile-time
// offsets from cpb): c0/c1 = hi of codes 0..31 / 32..63, d0/d1 = lo.
#define LOADC(P, qq) { \
    P##c0 = *(const f16x8*)(cpb + (qq) * 1024); \
    P##d0 = *(const f16x8*)(cpb + 16384 + (qq) * 1024); \
    P##c1 = *(const f16x8*)(cpb + 32768 + (qq) * 1024); \
    P##d1 = *(const f16x8*)(cpb + 49152 + (qq) * 1024); }

// 12 MFMAs: 4 independent chains (acc[ck][mt]), round-robin so each chain's
// dependent issues are 4 slots away. Products: ch*xh + ch*xl + cl*xh.
#define MFMAS(P) \
    __builtin_amdgcn_s_setprio(1); \
    acc[0][0] = MFMA16(P##c0, P##xh0, acc[0][0]); \
    acc[0][1] = MFMA16(P##c1, P##xh0, acc[0][1]); \
    acc[1][0] = MFMA16(P##c0, P##xh1, acc[1][0]); \
    acc[1][1] = MFMA16(P##c1, P##xh1, acc[1][1]); \
    acc[0][0] = MFMA16(P##c0, P##xl0, acc[0][0]); \
    acc[0][1] = MFMA16(P##c1, P##xl0, acc[0][1]); \
    acc[1][0] = MFMA16(P##c0, P##xl1, acc[1][0]); \
    acc[1][1] = MFMA16(P##c1, P##xl1, acc[1][1]); \
    acc[0][0] = MFMA16(P##d0, P##xh0, acc[0][0]); \
    acc[0][1] = MFMA16(P##d1, P##xh0, acc[0][1]); \
    acc[1][0] = MFMA16(P##d0, P##xh1, acc[1][0]); \
    acc[1][1] = MFMA16(P##d1, P##xh1, acc[1][1]); \
    __builtin_amdgcn_s_setprio(0);

__global__ __launch_bounds__(512, 2) void argmin_seg(
    const _Float16* __restrict__ Xp, const _Float16* __restrict__ Bp,
    const float* __restrict__ neF, unsigned long long* __restrict__ minpair) {
    __shared__ __align__(16) _Float16 Cs[64 * 512];   // 64 KB, nothing else

    const int tid  = threadIdx.x;
    const int lane = tid & 63;
    const int w    = tid >> 6;     // 0..7
    const int c32  = lane & 31;
    const int kg   = lane >> 5;

    const int rg      = blockIdx.x & 7;
    const int seg     = blockIdx.x >> 3;
    const int rowBase = rg * 2048;
    const int code0   = seg * 64;

    // stage code slab TRANSPOSED: LDS chunk j (1 KB, linear dest) holds
    // { slot 2*(j&31)+0 : codes 0..31 | slot 2*(j&31)+1 : codes 0..31 } of
    // code-half (j>>5). Lane l fetches global Bp[code0 + (j&32) + (l&31)]
    // slot (2*(j&31) + (l>>5)).  (16B-gather src; prologue-only, L2-hot.)
    #pragma unroll
    for (int i = 0; i < 8; ++i) {
        int j    = w * 8 + i;
        int code = code0 + (j & 32) + (lane & 31);
        int s    = ((j & 31) << 1) | (lane >> 5);
        load_lds16((const char*)Bp + ((size_t)code << 10) + (s << 4),
                   (char*)Cs + (j << 10));
    }
    __syncthreads();   // the only barrier

    // read base: lane offset c32*16 within a 512B slot-row, kg picks the
    // adjacent slot. Per q: 4 reads at compile-time offsets, each wave-
    // contiguous 1 KB -> conflict-free.
    const char* cpb = (const char*)Cs + (kg << 9) + (c32 << 4);

    const int wBase = rowBase + w * 256;   // 4 chunk-pairs of 64 rows per wave
    #pragma unroll 1
    for (int c2 = 0; c2 < 4; ++c2) {
        const int rb0 = (wBase >> 5) + c2 * 2;
        const char* xb0 = (const char*)Xp + (size_t)rb0 * 32768 + lane * 16;
        const char* xb1 = xb0 + 32768;
        f32x16 acc[2][2];   // [chunk][mt] - 4 independent MFMA chains, 64 AGPR
        #pragma unroll
        for (int i = 0; i < 16; ++i) {
            acc[0][0][i] = 0.0f; acc[0][1][i] = 0.0f;
            acc[1][0][i] = 0.0f; acc[1][1][i] = 0.0f;
        }

        DECL_STAGE(a)
        DECL_STAGE(b)
        LOADX(a, 0)
        LOADC(a, 0)
        #pragma unroll 1
        for (int q = 0; q < 16; q += 2) {
            LOADX(b, q + 1)
            LOADC(b, q + 1)
            MFMAS(a)
            LOADX(a, (q + 2) & 15)
            LOADC(a, (q + 2) & 15)
            MFMAS(b)
        }

        // epilogue: ne loaded here only (L1-hot after first iter). Code id of
        // acc[ck][mt][r] = code0 + mt*32 + 4*kg + (r&3) + 8*(r>>2); (mt,r)
        // ascending <=> id ascending; strict < => first(lowest-index)-wins.
        f32x4v ne4[2][4];
        #pragma unroll
        for (int mt = 0; mt < 2; ++mt)
            #pragma unroll
            for (int g2 = 0; g2 < 4; ++g2)
                ne4[mt][g2] = *(const f32x4v*)(neF + code0 + mt * 32 + g2 * 8 + 4 * kg);
        #pragma unroll
        for (int ck = 0; ck < 2; ++ck) {
            float best = 3.402823466e+38f;
            int   bi   = 0;
            #pragma unroll
            for (int mt = 0; mt < 2; ++mt)
                #pragma unroll
                for (int r = 0; r < 16; ++r) {
                    float d  = acc[ck][mt][r] + ne4[mt][r >> 2][r & 3];
                    int   id = code0 + mt * 32 + 4 * kg + ((r & 3) + 8 * (r >> 2));
                    if (d < best) { best = d; bi = id; }
                }
            float ov = __shfl_xor(best, 32, 64);
            int   oi = __shfl_xor(bi, 32, 64);
            if (ov < best || (ov == best && oi < bi)) { best = ov; bi = oi; }
            if (kg == 0) {
                int row = (rb0 + ck) * 32 + c32;
                unsigned u = __float_as_uint(best);
                u = (u & 0x80000000u) ? ~u : (u | 0x80000000u);   // total-order map
                atomicMin(&minpair[row],
                          (((unsigned long long)u) << 32) | (unsigned)bi);
            }
        }
    }
}

// decode packed min, gather codebook row, write quantized_sg + float index,
// histogram atomic + per-block SSE partials.
__global__ __launch_bounds__(256) void finalize_kernel(
    const float* __restrict__ x, const float* __restrict__ emb,
    const unsigned long long* __restrict__ minpair,
    float* __restrict__ out_q, float* __restrict__ out_idx,
    int* __restrict__ counts, float* __restrict__ parts) {
    __shared__ float rde[4], rdq[4];
    int wv   = threadIdx.x >> 6;
    int row  = (blockIdx.x << 2) + wv;
    int lane = threadIdx.x & 63;

    int bi = (int)(minpair[row] & 0xFFFFFFFFull);

    float4 xv = ((const float4*)(x   + (size_t)row * DDIM))[lane];
    float4 ev = ((const float4*)(emb + (size_t)bi  * DDIM))[lane];
    float4 q;
    q.x = xv.x + (ev.x - xv.x);
    q.y = xv.y + (ev.y - xv.y);
    q.z = xv.z + (ev.z - xv.z);
    q.w = xv.w + (ev.w - xv.w);
    ((float4*)(out_q + (size_t)row * DDIM))[lane] = q;

    float de = (ev.x - xv.x) * (ev.x - xv.x) + (ev.y - xv.y) * (ev.y - xv.y)
             + (ev.z - xv.z) * (ev.z - xv.z) + (ev.w - xv.w) * (ev.w - xv.w);
    float dq = (q.x - ev.x) * (q.x - ev.x) + (q.y - ev.y) * (q.y - ev.y)
             + (q.z - ev.z) * (q.z - ev.z) + (q.w - ev.w) * (q.w - ev.w);
    #pragma unroll
    for (int m = 32; m; m >>= 1) {
        de += __shfl_xor(de, m, 64);
        dq += __shfl_xor(dq, m, 64);
    }
    if (lane == 0) {
        out_idx[row] = (float)bi;
        atomicAdd(&counts[bi], 1);
        rde[wv] = de; rdq[wv] = dq;
    }
    __syncthreads();
    if (threadIdx.x == 0) {
        parts[blockIdx.x]        = rde[0] + rde[1] + rde[2] + rde[3];
        parts[4096 + blockIdx.x] = rdq[0] + rdq[1] + rdq[2] + rdq[3];
    }
}

__global__ __launch_bounds__(256) void scalars_kernel(
    const int* __restrict__ counts, const float* __restrict__ parts,
    float* __restrict__ out_loss, float* __restrict__ out_perp) {
    __shared__ float red[256], rde[256], rdq[256];
    float local = 0.0f, de = 0.0f, dq = 0.0f;
    for (int k = threadIdx.x; k < KCODES; k += 256) {
        float p = (float)counts[k] * (1.0f / (float)ND_ROWS);
        local += p * logf(p + 1e-10f);
    }
    for (int k = threadIdx.x; k < 4096; k += 256) {
        de += parts[k];
        dq += parts[4096 + k];
    }
    red[threadIdx.x] = local; rde[threadIdx.x] = de; rdq[threadIdx.x] = dq;
    __syncthreads();
    for (int s = 128; s; s >>= 1) {
        if (threadIdx.x < s) {
            red[threadIdx.x] += red[threadIdx.x + s];
            rde[threadIdx.x] += rde[threadIdx.x + s];
            rdq[threadIdx.x] += rdq[threadIdx.x + s];
        }
        __syncthreads();
    }
    if (threadIdx.x == 0) {
        *out_perp = expf(-red[0]);
        float invn = 1.0f / (float)(ND_ROWS * DDIM);
        *out_loss = rdq[0] * invn + 0.25f * (rde[0] * invn);
    }
}

extern "C" void kernel_launch(void* const* d_in, const int* in_sizes, int n_in,
                              void* d_out, int out_size, void* d_ws, size_t ws_size,
                              hipStream_t stream) {
    const float* x   = (const float*)d_in[0];
    const float* emb = (const float*)d_in[1];

    char* ws = (char*)d_ws;
    unsigned long long* minpair = (unsigned long long*)ws;         // 128 KB
    int*      counts = (int*)(ws + 131072);                        // 32 KB
    float*    parts  = (float*)(ws + 163840);                      // 32 KB
    float*    neF    = (float*)(ws + 196608);                      // 32 KB
    _Float16* Xp     = (_Float16*)(ws + 229376);                   // 16.8 MB
    _Float16* Bp     = (_Float16*)(ws + 17006592);                 // 8.4 MB

    float* out_q    = (float*)d_out;
    float* out_idx  = out_q + (size_t)ND_ROWS * DDIM;
    float* out_loss = out_idx + ND_ROWS;
    float* out_perp = out_loss + 1;

    hipMemsetAsync(minpair, 0xFF, ND_ROWS * sizeof(unsigned long long), stream);
    hipMemsetAsync(counts, 0, KCODES * sizeof(int), stream);

    prep_kernel<<<(KCODES + ND_ROWS) / 4, 256, 0, stream>>>(x, emb, Xp, Bp, neF);
    argmin_seg<<<NRG * NSEG, 512, 0, stream>>>(Xp, Bp, neF, minpair);
    finalize_kernel<<<ND_ROWS / 4, 256, 0, stream>>>(x, emb, minpair,
                                                     out_q, out_idx, counts, parts);
    scalars_kernel<<<1, 256, 0, stream>>>(counts, parts, out_loss, out_perp);
}